// Round 1
// baseline (1016.399 us; speedup 1.0000x reference)
//
#include <hip/hip_runtime.h>
#include <math.h>

#define B_SZ 1024
#define NMAX 21
#define NN 441            // 21*21
#define HNF 256
#define TOT_ROWS (B_SZ * NN)   // 451584
#define TILES_PER_BATCH 7      // 441 = 7*63
#define BM 63
#define BK 16

__device__ __forceinline__ float softplus_f(float x) {
    // matches jax.nn.softplus = logaddexp(x, 0)
    return fmaxf(x, 0.f) + log1pf(expf(-fabsf(x)));
}

// ---------------------------------------------------------------------------
// Kernel 1: fused  h = relu(gnn @ W1 + b1);  e2 = h @ W2 + b2 (raw, to D/W
// regions);  emb partial sums (atomicAdd). Grid: 1024*7 blocks, 256 threads.
// Each block: 63 rows (one batch) x 256 cols.
// ---------------------------------------------------------------------------
__global__ __launch_bounds__(256) void fused_mlp_kernel(
    const float* __restrict__ gnn, const float* __restrict__ W1,
    const float* __restrict__ b1,  const float* __restrict__ W2,
    const float* __restrict__ b2,
    float* __restrict__ Dreg, float* __restrict__ Wreg, float* __restrict__ emb)
{
    __shared__ __align__(16) float As[BK][68];     // A^T tile, padded stride
    __shared__ __align__(16) float Bs[BK * 256];   // B tile, linear
    __shared__ float embp[4][256];

    const int t  = threadIdx.x;
    const int tx = t & 15, ty = t >> 4;
    const int batch = blockIdx.x / TILES_PER_BATCH;
    const int tile  = blockIdx.x % TILES_PER_BATCH;
    const long row0 = (long)batch * NN + (long)tile * BM;

    // A-load mapping: thread loads row (t>>2), k-chunk (t&3)*4
    long arow = row0 + (t >> 2);
    if (arow > (long)TOT_ROWS - 1) arow = TOT_ROWS - 1;   // clamp (masked later)
    const float* Ag = gnn + arow * HNF + ((t & 3) << 2);

    float acc[4][16];
    #pragma unroll
    for (int i = 0; i < 4; i++)
        #pragma unroll
        for (int c = 0; c < 16; c++) acc[i][c] = 0.f;

    for (int k0 = 0; k0 < HNF; k0 += BK) {
        float4 av = *(const float4*)(Ag + k0);
        float4 bv[4];
        #pragma unroll
        for (int p = 0; p < 4; p++) {
            int idx4 = t + p * 256;            // 0..1023 float4's
            int kk = idx4 >> 6;                // row within BK
            int c4 = (idx4 & 63) << 2;         // col
            bv[p] = *(const float4*)(W1 + (long)(k0 + kk) * HNF + c4);
        }
        __syncthreads();
        {
            int kb = (t & 3) << 2, r = t >> 2;
            As[kb + 0][r] = av.x; As[kb + 1][r] = av.y;
            As[kb + 2][r] = av.z; As[kb + 3][r] = av.w;
        }
        #pragma unroll
        for (int p = 0; p < 4; p++)
            *(float4*)&Bs[(t + p * 256) << 2] = bv[p];
        __syncthreads();

        #pragma unroll
        for (int k = 0; k < BK; k++) {
            float4 a = *(const float4*)&As[k][ty << 2];
            float4 bq[4];
            #pragma unroll
            for (int j = 0; j < 4; j++)
                bq[j] = *(const float4*)&Bs[k * 256 + j * 64 + (tx << 2)];
            #pragma unroll
            for (int i = 0; i < 4; i++) {
                float ai = (i == 0) ? a.x : (i == 1) ? a.y : (i == 2) ? a.z : a.w;
                #pragma unroll
                for (int j = 0; j < 4; j++) {
                    acc[i][j*4+0] += ai * bq[j].x;
                    acc[i][j*4+1] += ai * bq[j].y;
                    acc[i][j*4+2] += ai * bq[j].z;
                    acc[i][j*4+3] += ai * bq[j].w;
                }
            }
        }
    }

    // ---- epilogue: bias + relu (in place) ----
    float b1r[16], w20[16], w21[16];
    #pragma unroll
    for (int j = 0; j < 4; j++)
        #pragma unroll
        for (int jj = 0; jj < 4; jj++) {
            int col = j * 64 + (tx << 2) + jj;
            b1r[j*4+jj] = b1[col];
            w20[j*4+jj] = W2[col * 2 + 0];
            w21[j*4+jj] = W2[col * 2 + 1];
        }
    #pragma unroll
    for (int i = 0; i < 4; i++)
        #pragma unroll
        for (int c = 0; c < 16; c++)
            acc[i][c] = fmaxf(acc[i][c] + b1r[c], 0.f);

    // ---- e2 = h @ W2 + b2 : per-row partial over this thread's 16 cols ----
    float ps0[4] = {0,0,0,0}, ps1[4] = {0,0,0,0};
    #pragma unroll
    for (int i = 0; i < 4; i++)
        #pragma unroll
        for (int c = 0; c < 16; c++) {
            ps0[i] += acc[i][c] * w20[c];
            ps1[i] += acc[i][c] * w21[c];
        }
    #pragma unroll
    for (int off = 1; off < 16; off <<= 1)
        #pragma unroll
        for (int i = 0; i < 4; i++) {
            ps0[i] += __shfl_xor(ps0[i], off);
            ps1[i] += __shfl_xor(ps1[i], off);
        }
    if (tx == 0) {
        float b20 = b2[0], b21 = b2[1];
        #pragma unroll
        for (int i = 0; i < 4; i++) {
            int rl = (ty << 2) + i;
            if (rl < BM) {
                size_t idx = (size_t)batch * NN + (size_t)tile * BM + rl;
                Dreg[idx] = ps0[i] + b20;   // raw e2 ch0 (symmetrized later)
                Wreg[idx] = ps1[i] + b21;   // raw e2 ch1
            }
        }
    }

    // ---- emb: column sums over valid rows ----
    float cp[16];
    #pragma unroll
    for (int c = 0; c < 16; c++) {
        float s = 0.f;
        #pragma unroll
        for (int i = 0; i < 4; i++) {
            int rl = (ty << 2) + i;
            s += (rl < BM) ? acc[i][c] : 0.f;
        }
        cp[c] = s;
    }
    #pragma unroll
    for (int off = 16; off < 64; off <<= 1)
        #pragma unroll
        for (int c = 0; c < 16; c++) cp[c] += __shfl_xor(cp[c], off);
    if ((ty & 3) == 0) {
        int w = ty >> 2;
        #pragma unroll
        for (int j = 0; j < 4; j++)
            #pragma unroll
            for (int jj = 0; jj < 4; jj++)
                embp[w][j * 64 + (tx << 2) + jj] = cp[j*4+jj];
    }
    __syncthreads();
    {
        int c = t;
        float s = embp[0][c] + embp[1][c] + embp[2][c] + embp[3][c];
        atomicAdd(emb + (size_t)batch * 256 + c, s);
    }
}

// ---------------------------------------------------------------------------
// Kernel 2: in-place symmetrize + softplus. One thread per unordered pair.
// ---------------------------------------------------------------------------
__global__ __launch_bounds__(256) void sym_kernel(float* __restrict__ Dreg,
                                                  float* __restrict__ Wreg)
{
    int t = blockIdx.x * 256 + threadIdx.x;
    const int PAIRS = (NMAX * (NMAX + 1)) / 2;   // 231
    if (t >= B_SZ * PAIRS) return;
    int b = t / PAIRS, p = t % PAIRS;
    int i = 0;
    while (p >= NMAX - i) { p -= NMAX - i; i++; }
    int j = i + p;
    size_t base = (size_t)b * NN;
    float a0 = Dreg[base + i * NMAX + j], a1 = Dreg[base + j * NMAX + i];
    float d  = (i == j) ? 0.f : softplus_f(a0 + a1);
    Dreg[base + i * NMAX + j] = d; Dreg[base + j * NMAX + i] = d;
    float w0 = Wreg[base + i * NMAX + j], w1 = Wreg[base + j * NMAX + i];
    float ws = softplus_f(w0 + w1);
    Wreg[base + i * NMAX + j] = ws; Wreg[base + j * NMAX + i] = ws;
}

// ---------------------------------------------------------------------------
// Kernel 3: per-batch MDS reconstruction. 1 block = 1 wave = 1 batch.
// ---------------------------------------------------------------------------
__global__ __launch_bounds__(64) void recon_kernel(
    const float* __restrict__ Dm, const float* __restrict__ Wm,
    const float* __restrict__ un, const float* __restrict__ xn,
    float* __restrict__ Xo)
{
    const int b = blockIdx.x, l = threadIdx.x;
    __shared__ float D[NMAX][22], Wt[NMAX][22], A[NMAX][22], m[NMAX][22];
    __shared__ float X[NMAX][3], u[24], rs[NMAX], cs[NMAX];

    const float* Db = Dm + (size_t)b * NN;
    const float* Wb = Wm + (size_t)b * NN;
    for (int idx = l; idx < NN; idx += 64) {
        int i = idx / NMAX, j = idx % NMAX;
        D[i][j]  = Db[idx];
        Wt[i][j] = Wb[idx];
    }
    __syncthreads();
    if (l < NMAX) {
        float s = 0.f, c = 0.f;
        for (int j = 0; j < NMAX; j++) { s += D[l][j]; c += D[j][l]; }
        rs[l] = s; cs[l] = c;
    }
    __syncthreads();
    float mean = 0.f;
    for (int i = 0; i < NMAX; i++) mean += rs[i];
    mean *= (1.f / (float)(NN));
    for (int idx = l; idx < NN; idx += 64) {
        int i = idx / NMAX, j = idx % NMAX;
        A[i][j] = -0.5f * (D[i][j] - cs[j] * (1.f/21.f) - rs[i] * (1.f/21.f) + mean);
    }
    __syncthreads();

    // deflated power iteration, k=3, 10 steps each
    for (int e = 0; e < 3; e++) {
        if (l < NMAX) u[l] = un[(size_t)b * 63 + e * NMAX + l];
        __syncthreads();
        for (int s = 0; s < 10; s++) {
            float n2 = 0.f;
            for (int q = 0; q < NMAX; q++) { float v = u[q]; n2 += v * v; }
            float n = fmaxf(sqrtf(n2), 1e-3f);
            float uv = (l < NMAX) ? u[l] / n : 0.f;
            __syncthreads();
            if (l < NMAX) u[l] = uv;
            __syncthreads();
            float accv = 0.f;
            if (l < NMAX)
                for (int q = 0; q < NMAX; q++) accv += A[l][q] * u[q];
            __syncthreads();
            if (l < NMAX) u[l] = accv;
            __syncthreads();
        }
        float e2 = 0.f;
        for (int q = 0; q < NMAX; q++) { float v = u[q]; e2 += v * v; }
        float sc = 1.f / sqrtf(sqrtf(e2 + 0.01f));
        float uf = (l < NMAX) ? u[l] * sc : 0.f;
        __syncthreads();
        if (l < NMAX) u[l] = uf;
        __syncthreads();
        if (l < NMAX) {
            X[l][e] = uf;
            for (int q = 0; q < NMAX; q++) A[l][q] -= uf * u[q];
        }
        __syncthreads();
    }
    if (l < NMAX)
        for (int i = 0; i < 3; i++) X[l][i] += xn[(size_t)b * 63 + l * 3 + i];
    __syncthreads();

    // 100 clipped gradient-descent steps
    for (int tstep = 0; tstep < 100; tstep++) {
        for (int idx = l; idx < NN; idx += 64) {
            int i = idx / NMAX, j = idx % NMAX;
            float dx = X[j][0] - X[i][0];
            float dy = X[j][1] - X[i][1];
            float dz = X[j][2] - X[i][2];
            float s = dx*dx + dy*dy + dz*dz + 0.01f;
            m[i][j] = Wt[i][j] * (D[i][j] - s);
        }
        __syncthreads();
        float nx = 0.f, ny = 0.f, nz = 0.f;
        if (l < NMAX) {
            float xp0 = X[l][0], xp1 = X[l][1], xp2 = X[l][2];
            float gx = 0.f, gy = 0.f, gz = 0.f;
            for (int q = 0; q < NMAX; q++) {
                float c = m[l][q] + m[q][l];
                gx += c * (xp0 - X[q][0]);
                gy += c * (xp1 - X[q][1]);
                gz += c * (xp2 - X[q][2]);
            }
            // dX = -0.1 * grad ; grad = -4 * sum(...)  =>  dX = 0.4 * sum(...)
            float d0 = 0.4f * gx, d1 = 0.4f * gy, d2 = 0.4f * gz;
            float speed = sqrtf(d0*d0 + d1*d1 + d2*d2 + 1e-3f);
            float alpha = 0.1f + 4.9f * (100.f - (float)tstep) * 0.01f;
            float scale = alpha * tanhf(speed / alpha) / speed;
            nx = xp0 + d0 * scale; ny = xp1 + d1 * scale; nz = xp2 + d2 * scale;
        }
        __syncthreads();
        if (l < NMAX) { X[l][0] = nx; X[l][1] = ny; X[l][2] = nz; }
        __syncthreads();
    }
    if (l < NMAX) {
        Xo[(size_t)b * 63 + l * 3 + 0] = X[l][0];
        Xo[(size_t)b * 63 + l * 3 + 1] = X[l][1];
        Xo[(size_t)b * 63 + l * 3 + 2] = X[l][2];
    }
}

// ---------------------------------------------------------------------------
extern "C" void kernel_launch(void* const* d_in, const int* in_sizes, int n_in,
                              void* d_out, int out_size, void* d_ws, size_t ws_size,
                              hipStream_t stream) {
    const float* gnn = (const float*)d_in[0];
    const float* W1  = (const float*)d_in[1];
    const float* b1  = (const float*)d_in[2];
    const float* W2  = (const float*)d_in[3];
    const float* b2  = (const float*)d_in[4];
    const float* un  = (const float*)d_in[5];
    const float* xn  = (const float*)d_in[6];

    float* out  = (float*)d_out;
    float* Dreg = out;                                  // [1024*441]
    float* Wreg = out + (size_t)TOT_ROWS;               // [1024*441]
    float* emb  = out + (size_t)2 * TOT_ROWS;           // [1024*256]
    float* Xo   = out + (size_t)2 * TOT_ROWS + B_SZ*256;// [1024*63]

    hipMemsetAsync(emb, 0, (size_t)B_SZ * 256 * sizeof(float), stream);

    fused_mlp_kernel<<<dim3(B_SZ * TILES_PER_BATCH), dim3(256), 0, stream>>>(
        gnn, W1, b1, W2, b2, Dreg, Wreg, emb);

    const int PAIRS = (NMAX * (NMAX + 1)) / 2;          // 231
    int sym_threads = B_SZ * PAIRS;                     // 236544
    sym_kernel<<<dim3((sym_threads + 255) / 256), dim3(256), 0, stream>>>(Dreg, Wreg);

    recon_kernel<<<dim3(B_SZ), dim3(64), 0, stream>>>(Dreg, Wreg, un, xn, Xo);
}

// Round 2
// 473.406 us; speedup vs baseline: 2.1470x; 2.1470x over previous
//
#include <hip/hip_runtime.h>
#include <hip/hip_fp16.h>
#include <math.h>

#define B_SZ 1024
#define NMAX 21
#define NN 441            // 21*21
#define HNF 256
#define TOT_ROWS (B_SZ * NN)   // 451584
#define TILES_PER_BATCH 7      // 441 = 7*63
#define BMV 63                 // valid rows per tile (row 63 is pad)

typedef _Float16 half8 __attribute__((ext_vector_type(8)));
typedef float float4v __attribute__((ext_vector_type(4)));

__device__ __forceinline__ float softplus_f(float x) {
    return fmaxf(x, 0.f) + log1pf(expf(-fabsf(x)));
}

// ---------------------------------------------------------------------------
// Pack W1 into MFMA B-fragment order, split into fp16 hi/lo.
// Fragment (kstep s in 0..7, nfrag f in 0..15): lane l, elem j holds
// W1[s*32 + (l>>4)*8 + j][f*16 + (l&15)].  Linear index = ((s*16+f)*64+l)*8+j.
// ---------------------------------------------------------------------------
__global__ __launch_bounds__(256) void pack_w1(const float* __restrict__ W1,
                                               _Float16* __restrict__ B0p,
                                               _Float16* __restrict__ B1p)
{
    int id = blockIdx.x * 256 + threadIdx.x;   // 0..65535
    int j = id & 7, l = (id >> 3) & 63, f = (id >> 9) & 15, s = id >> 13;
    int k = s * 32 + ((l >> 4) << 3) + j;
    int c = (f << 4) + (l & 15);
    float v = W1[k * HNF + c];
    _Float16 h0 = (_Float16)v;
    B0p[id] = h0;
    B1p[id] = (_Float16)(v - (float)h0);
}

// ---------------------------------------------------------------------------
// Kernel 1: fused  h = relu(gnn @ W1 + b1)  via fp16-split MFMA (3 products,
// ~fp32 accuracy);  e2 = h @ W2 + b2 (raw, to D/W regions);  emb partials.
// Grid: 1024*7 blocks, 256 threads (4 waves). Block: 64 rows (63 valid) x 256.
// Wave w owns cols [w*64, w*64+64).
// ---------------------------------------------------------------------------
__global__ __launch_bounds__(256) void fused_mlp_mfma(
    const float* __restrict__ gnn,
    const _Float16* __restrict__ B0p, const _Float16* __restrict__ B1p,
    const float* __restrict__ b1, const float* __restrict__ W2,
    const float* __restrict__ b2,
    float* __restrict__ Dreg, float* __restrict__ Wreg, float* __restrict__ emb)
{
    // 96B row stride (48 halves): 16B-aligned b128 ops, uniform bank spread
    __shared__ _Float16 A0[64][48];
    __shared__ _Float16 A1[64][48];
    __shared__ float red0[4][64];
    __shared__ float red1[4][64];

    const int t = threadIdx.x;
    const int w = t >> 6, l = t & 63;
    const int batch = blockIdx.x / TILES_PER_BATCH;
    const int tile  = blockIdx.x % TILES_PER_BATCH;
    const long row0 = (long)batch * NN + (long)tile * BMV;

    // staging mapping: thread -> (row sr, k-quad skq of 8 elems)
    const int sr  = t >> 2;
    const int skq = t & 3;
    long arow = row0 + sr;
    if (arow >= (long)TOT_ROWS) arow = TOT_ROWS - 1;   // pad row of last block
    const float* asrc = gnn + arow * HNF + (skq << 3);

    // fragment mapping
    const int frow = l & 15;
    const int fk   = l >> 4;     // k-group, elems fk*8..fk*8+7

    float4v acc[4][4];
    #pragma unroll
    for (int m = 0; m < 4; m++)
        #pragma unroll
        for (int n = 0; n < 4; n++)
            acc[m][n] = (float4v){0.f, 0.f, 0.f, 0.f};

    for (int kk = 0; kk < 8; kk++) {
        // ---- stage A (fp32 -> fp16 hi/lo) ----
        float4 f0 = *(const float4*)(asrc + kk * 32);
        float4 f1 = *(const float4*)(asrc + kk * 32 + 4);
        float fv[8] = {f0.x, f0.y, f0.z, f0.w, f1.x, f1.y, f1.z, f1.w};
        half8 v0, v1;
        #pragma unroll
        for (int i = 0; i < 8; i++) {
            _Float16 h = (_Float16)fv[i];
            v0[i] = h;
            v1[i] = (_Float16)(fv[i] - (float)h);
        }
        __syncthreads();   // previous iter's frag reads complete
        *(half8*)&A0[sr][skq << 3] = v0;
        *(half8*)&A1[sr][skq << 3] = v1;
        __syncthreads();

        // ---- B fragments from L2-resident packed W1 ----
        half8 b0f[4], b1f[4];
        #pragma unroll
        for (int n = 0; n < 4; n++) {
            int nf = (w << 2) + n;
            size_t off = (size_t)(((kk << 4) + nf) << 6 | l) << 3;
            b0f[n] = *(const half8*)(B0p + off);
            b1f[n] = *(const half8*)(B1p + off);
        }
        // ---- A fragments from LDS ----
        half8 a0f[4], a1f[4];
        #pragma unroll
        for (int m = 0; m < 4; m++) {
            a0f[m] = *(const half8*)&A0[(m << 4) + frow][fk << 3];
            a1f[m] = *(const half8*)&A1[(m << 4) + frow][fk << 3];
        }
        // ---- 48 MFMAs: acc += a0*b0 + a0*b1 + a1*b0 ----
        #pragma unroll
        for (int m = 0; m < 4; m++)
            #pragma unroll
            for (int n = 0; n < 4; n++) {
                acc[m][n] = __builtin_amdgcn_mfma_f32_16x16x32_f16(a0f[m], b0f[n], acc[m][n], 0, 0, 0);
                acc[m][n] = __builtin_amdgcn_mfma_f32_16x16x32_f16(a0f[m], b1f[n], acc[m][n], 0, 0, 0);
                acc[m][n] = __builtin_amdgcn_mfma_f32_16x16x32_f16(a1f[m], b0f[n], acc[m][n], 0, 0, 0);
            }
    }

    // ---- epilogue: bias + relu, e2 row-dots, emb col partials ----
    // C frag layout: col = n*16 + (l&15) (+w*64), row = m*16 + (l>>4)*4 + j
    const int colbase = (w << 6) + frow;
    float w20[4], w21[4], b1v[4];
    #pragma unroll
    for (int n = 0; n < 4; n++) {
        int c = colbase + (n << 4);
        b1v[n] = b1[c];
        w20[n] = W2[2 * c];
        w21[n] = W2[2 * c + 1];
    }
    float ps0[4][4], ps1[4][4], embp[4] = {0.f, 0.f, 0.f, 0.f};
    #pragma unroll
    for (int m = 0; m < 4; m++)
        #pragma unroll
        for (int j = 0; j < 4; j++) { ps0[m][j] = 0.f; ps1[m][j] = 0.f; }

    #pragma unroll
    for (int m = 0; m < 4; m++)
        #pragma unroll
        for (int n = 0; n < 4; n++)
            #pragma unroll
            for (int j = 0; j < 4; j++) {
                float h = fmaxf(acc[m][n][j] + b1v[n], 0.f);
                ps0[m][j] += h * w20[n];
                ps1[m][j] += h * w21[n];
                int row = (m << 4) + (fk << 2) + j;
                if (row < BMV) embp[n] += h;     // exclude pad row 63
            }

    // e2: reduce over 16 col-lanes
    #pragma unroll
    for (int off = 1; off < 16; off <<= 1)
        #pragma unroll
        for (int m = 0; m < 4; m++)
            #pragma unroll
            for (int j = 0; j < 4; j++) {
                ps0[m][j] += __shfl_xor(ps0[m][j], off);
                ps1[m][j] += __shfl_xor(ps1[m][j], off);
            }
    if (frow == 0) {
        #pragma unroll
        for (int m = 0; m < 4; m++)
            #pragma unroll
            for (int j = 0; j < 4; j++) {
                int row = (m << 4) + (fk << 2) + j;
                red0[w][row] = ps0[m][j];
                red1[w][row] = ps1[m][j];
            }
    }

    // emb: reduce over k-groups (rows), lanes 0..15 hold col sums
    #pragma unroll
    for (int n = 0; n < 4; n++) {
        embp[n] += __shfl_xor(embp[n], 16);
        embp[n] += __shfl_xor(embp[n], 32);
    }
    if (l < 16) {
        #pragma unroll
        for (int n = 0; n < 4; n++)
            atomicAdd(emb + (size_t)batch * 256 + (w << 6) + (n << 4) + l, embp[n]);
    }

    __syncthreads();
    if (t < 64) {
        float v0 = red0[0][t] + red0[1][t] + red0[2][t] + red0[3][t] + b2[0];
        float v1 = red1[0][t] + red1[1][t] + red1[2][t] + red1[3][t] + b2[1];
        if (t < BMV) {
            Dreg[row0 + t] = v0;   // raw e2 ch0 (symmetrized later)
            Wreg[row0 + t] = v1;
        }
    }
}

// ---------------------------------------------------------------------------
// Kernel 2: in-place symmetrize + softplus. One thread per unordered pair.
// ---------------------------------------------------------------------------
__global__ __launch_bounds__(256) void sym_kernel(float* __restrict__ Dreg,
                                                  float* __restrict__ Wreg)
{
    int t = blockIdx.x * 256 + threadIdx.x;
    const int PAIRS = (NMAX * (NMAX + 1)) / 2;   // 231
    if (t >= B_SZ * PAIRS) return;
    int b = t / PAIRS, p = t % PAIRS;
    int i = 0;
    while (p >= NMAX - i) { p -= NMAX - i; i++; }
    int j = i + p;
    size_t base = (size_t)b * NN;
    float a0 = Dreg[base + i * NMAX + j], a1 = Dreg[base + j * NMAX + i];
    float d  = (i == j) ? 0.f : softplus_f(a0 + a1);
    Dreg[base + i * NMAX + j] = d; Dreg[base + j * NMAX + i] = d;
    float w0 = Wreg[base + i * NMAX + j], w1 = Wreg[base + j * NMAX + i];
    float ws = softplus_f(w0 + w1);
    Wreg[base + i * NMAX + j] = ws; Wreg[base + j * NMAX + i] = ws;
}

// ---------------------------------------------------------------------------
// Kernel 3: per-batch MDS reconstruction. 1 block = 1 wave = 1 batch.
// ---------------------------------------------------------------------------
__global__ __launch_bounds__(64) void recon_kernel(
    const float* __restrict__ Dm, const float* __restrict__ Wm,
    const float* __restrict__ un, const float* __restrict__ xn,
    float* __restrict__ Xo)
{
    const int b = blockIdx.x, l = threadIdx.x;
    __shared__ float D[NMAX][22], Wt[NMAX][22], A[NMAX][22], m[NMAX][22];
    __shared__ float X[NMAX][3], u[24], rs[NMAX], cs[NMAX];

    const float* Db = Dm + (size_t)b * NN;
    const float* Wb = Wm + (size_t)b * NN;
    for (int idx = l; idx < NN; idx += 64) {
        int i = idx / NMAX, j = idx % NMAX;
        D[i][j]  = Db[idx];
        Wt[i][j] = Wb[idx];
    }
    __syncthreads();
    if (l < NMAX) {
        float s = 0.f, c = 0.f;
        for (int j = 0; j < NMAX; j++) { s += D[l][j]; c += D[j][l]; }
        rs[l] = s; cs[l] = c;
    }
    __syncthreads();
    float mean = 0.f;
    for (int i = 0; i < NMAX; i++) mean += rs[i];
    mean *= (1.f / (float)(NN));
    for (int idx = l; idx < NN; idx += 64) {
        int i = idx / NMAX, j = idx % NMAX;
        A[i][j] = -0.5f * (D[i][j] - cs[j] * (1.f/21.f) - rs[i] * (1.f/21.f) + mean);
    }
    __syncthreads();

    // deflated power iteration, k=3, 10 steps each
    for (int e = 0; e < 3; e++) {
        if (l < NMAX) u[l] = un[(size_t)b * 63 + e * NMAX + l];
        __syncthreads();
        for (int s = 0; s < 10; s++) {
            float n2 = 0.f;
            for (int q = 0; q < NMAX; q++) { float v = u[q]; n2 += v * v; }
            float n = fmaxf(sqrtf(n2), 1e-3f);
            float uv = (l < NMAX) ? u[l] / n : 0.f;
            __syncthreads();
            if (l < NMAX) u[l] = uv;
            __syncthreads();
            float accv = 0.f;
            if (l < NMAX)
                for (int q = 0; q < NMAX; q++) accv += A[l][q] * u[q];
            __syncthreads();
            if (l < NMAX) u[l] = accv;
            __syncthreads();
        }
        float e2 = 0.f;
        for (int q = 0; q < NMAX; q++) { float v = u[q]; e2 += v * v; }
        float sc = 1.f / sqrtf(sqrtf(e2 + 0.01f));
        float uf = (l < NMAX) ? u[l] * sc : 0.f;
        __syncthreads();
        if (l < NMAX) u[l] = uf;
        __syncthreads();
        if (l < NMAX) {
            X[l][e] = uf;
            for (int q = 0; q < NMAX; q++) A[l][q] -= uf * u[q];
        }
        __syncthreads();
    }
    if (l < NMAX)
        for (int i = 0; i < 3; i++) X[l][i] += xn[(size_t)b * 63 + l * 3 + i];
    __syncthreads();

    // 100 clipped gradient-descent steps
    for (int tstep = 0; tstep < 100; tstep++) {
        for (int idx = l; idx < NN; idx += 64) {
            int i = idx / NMAX, j = idx % NMAX;
            float dx = X[j][0] - X[i][0];
            float dy = X[j][1] - X[i][1];
            float dz = X[j][2] - X[i][2];
            float s = dx*dx + dy*dy + dz*dz + 0.01f;
            m[i][j] = Wt[i][j] * (D[i][j] - s);
        }
        __syncthreads();
        float nx = 0.f, ny = 0.f, nz = 0.f;
        if (l < NMAX) {
            float xp0 = X[l][0], xp1 = X[l][1], xp2 = X[l][2];
            float gx = 0.f, gy = 0.f, gz = 0.f;
            for (int q = 0; q < NMAX; q++) {
                float c = m[l][q] + m[q][l];
                gx += c * (xp0 - X[q][0]);
                gy += c * (xp1 - X[q][1]);
                gz += c * (xp2 - X[q][2]);
            }
            float d0 = 0.4f * gx, d1 = 0.4f * gy, d2 = 0.4f * gz;
            float speed = sqrtf(d0*d0 + d1*d1 + d2*d2 + 1e-3f);
            float alpha = 0.1f + 4.9f * (100.f - (float)tstep) * 0.01f;
            float scale = alpha * tanhf(speed / alpha) / speed;
            nx = xp0 + d0 * scale; ny = xp1 + d1 * scale; nz = xp2 + d2 * scale;
        }
        __syncthreads();
        if (l < NMAX) { X[l][0] = nx; X[l][1] = ny; X[l][2] = nz; }
        __syncthreads();
    }
    if (l < NMAX) {
        Xo[(size_t)b * 63 + l * 3 + 0] = X[l][0];
        Xo[(size_t)b * 63 + l * 3 + 1] = X[l][1];
        Xo[(size_t)b * 63 + l * 3 + 2] = X[l][2];
    }
}

// ---------------------------------------------------------------------------
extern "C" void kernel_launch(void* const* d_in, const int* in_sizes, int n_in,
                              void* d_out, int out_size, void* d_ws, size_t ws_size,
                              hipStream_t stream) {
    const float* gnn = (const float*)d_in[0];
    const float* W1  = (const float*)d_in[1];
    const float* b1  = (const float*)d_in[2];
    const float* W2  = (const float*)d_in[3];
    const float* b2  = (const float*)d_in[4];
    const float* un  = (const float*)d_in[5];
    const float* xn  = (const float*)d_in[6];

    float* out  = (float*)d_out;
    float* Dreg = out;                                  // [1024*441]
    float* Wreg = out + (size_t)TOT_ROWS;               // [1024*441]
    float* emb  = out + (size_t)2 * TOT_ROWS;           // [1024*256]
    float* Xo   = out + (size_t)2 * TOT_ROWS + B_SZ*256;// [1024*63]

    _Float16* B0p = (_Float16*)d_ws;                    // 65536 halves
    _Float16* B1p = B0p + 65536;                        // 65536 halves (256KB total)

    pack_w1<<<dim3(256), dim3(256), 0, stream>>>(W1, B0p, B1p);
    hipMemsetAsync(emb, 0, (size_t)B_SZ * 256 * sizeof(float), stream);

    fused_mlp_mfma<<<dim3(B_SZ * TILES_PER_BATCH), dim3(256), 0, stream>>>(
        gnn, B0p, B1p, b1, W2, b2, Dreg, Wreg, emb);

    const int PAIRS = (NMAX * (NMAX + 1)) / 2;          // 231
    int sym_threads = B_SZ * PAIRS;                     // 236544
    sym_kernel<<<dim3((sym_threads + 255) / 256), dim3(256), 0, stream>>>(Dreg, Wreg);

    recon_kernel<<<dim3(B_SZ), dim3(64), 0, stream>>>(Dreg, Wreg, un, xn, Xo);
}

// Round 3
// 376.696 us; speedup vs baseline: 2.6982x; 1.2567x over previous
//
#include <hip/hip_runtime.h>
#include <hip/hip_fp16.h>
#include <math.h>

#define B_SZ 1024
#define NMAX 21
#define NN 441            // 21*21
#define HNF 256
#define TOT_ROWS (B_SZ * NN)   // 451584
#define TILES_PER_BATCH 7      // 441 = 7*63
#define BMV 63                 // valid rows per tile (row 63 is pad)

typedef _Float16 half8 __attribute__((ext_vector_type(8)));
typedef float float4v __attribute__((ext_vector_type(4)));

__device__ __forceinline__ float softplus_f(float x) {
    return fmaxf(x, 0.f) + log1pf(expf(-fabsf(x)));
}

// ---------------------------------------------------------------------------
// Pack W1 into MFMA B-fragment order, split into fp16 hi/lo.
// Fragment (kstep s in 0..7, nfrag f in 0..15): lane l, elem j holds
// W1[s*32 + (l>>4)*8 + j][f*16 + (l&15)].  Linear index = ((s*16+f)*64+l)*8+j.
// ---------------------------------------------------------------------------
__global__ __launch_bounds__(256) void pack_w1(const float* __restrict__ W1,
                                               _Float16* __restrict__ B0p,
                                               _Float16* __restrict__ B1p)
{
    int id = blockIdx.x * 256 + threadIdx.x;   // 0..65535
    int j = id & 7, l = (id >> 3) & 63, f = (id >> 9) & 15, s = id >> 13;
    int k = s * 32 + ((l >> 4) << 3) + j;
    int c = (f << 4) + (l & 15);
    float v = W1[k * HNF + c];
    _Float16 h0 = (_Float16)v;
    B0p[id] = h0;
    B1p[id] = (_Float16)(v - (float)h0);
}

// ---------------------------------------------------------------------------
// Kernel 1: fused  h = relu(gnn @ W1 + b1)  via fp16-split MFMA (3 products),
// e2 = h @ W2 + b2 (raw -> D/W regions), emb partials.
// Grid: 1024*7 blocks, 256 threads (4 waves). Block: 64 rows (63 valid) x 256.
// Single-stage full-K LDS tile in fragment-linear order; ONE barrier, then a
// barrier-free 8-kstep MFMA loop (B from L2, A from LDS).
// ---------------------------------------------------------------------------
__global__ __launch_bounds__(256) void fused_mlp_mfma(
    const float* __restrict__ gnn,
    const _Float16* __restrict__ B0p, const _Float16* __restrict__ B1p,
    const float* __restrict__ b1, const float* __restrict__ W2,
    const float* __restrict__ b2,
    float* __restrict__ Dreg, float* __restrict__ Wreg, float* __restrict__ emb)
{
    // fragment-linear: half index ((kk*4 + m)*64 + l)*8  -> 32KB each
    __shared__ _Float16 A0[16384];
    __shared__ _Float16 A1[16384];
    __shared__ float red0[4][64];
    __shared__ float red1[4][64];

    const int t = threadIdx.x;
    const int w = t >> 6, l = t & 63;
    const int batch = blockIdx.x / TILES_PER_BATCH;
    const int tile  = blockIdx.x % TILES_PER_BATCH;
    const long row0 = (long)batch * NN + (long)tile * BMV;

    // staging mapping: thread -> (row sr, col-group skq of 8 within each k32)
    const int sr  = t >> 2;      // 0..63
    const int skq = t & 3;       // 0..3
    long arow = row0 + sr;
    if (arow >= (long)TOT_ROWS) arow = TOT_ROWS - 1;   // pad row of last block
    const float* asrc = gnn + arow * HNF + (skq << 3);

    // fragment mapping for compute
    const int frow = l & 15;
    const int fk   = l >> 4;

    // ---- prologue: load whole 64x256 A tile ----
    float4 fr[16];
    #pragma unroll
    for (int kk = 0; kk < 8; kk++) {
        fr[2*kk]     = *(const float4*)(asrc + kk * 32);
        fr[2*kk + 1] = *(const float4*)(asrc + kk * 32 + 4);
    }
    // convert fp32 -> fp16 hi/lo, write fragment-linear LDS
    const int wbase = ((skq << 4) | (sr & 15));   // lane index this thread fills
    const int wm    = sr >> 4;                    // m-frag of this row
    #pragma unroll
    for (int kk = 0; kk < 8; kk++) {
        float fv[8] = {fr[2*kk].x, fr[2*kk].y, fr[2*kk].z, fr[2*kk].w,
                       fr[2*kk+1].x, fr[2*kk+1].y, fr[2*kk+1].z, fr[2*kk+1].w};
        half8 v0, v1;
        #pragma unroll
        for (int i = 0; i < 8; i++) {
            _Float16 h = (_Float16)fv[i];
            v0[i] = h;
            v1[i] = (_Float16)(fv[i] - (float)h);
        }
        int base = (((kk << 2) + wm) << 6 | wbase) << 3;
        *(half8*)&A0[base] = v0;
        *(half8*)&A1[base] = v1;
    }
    __syncthreads();

    // ---- barrier-free MFMA loop ----
    float4v acc[4][4];
    #pragma unroll
    for (int m = 0; m < 4; m++)
        #pragma unroll
        for (int n = 0; n < 4; n++)
            acc[m][n] = (float4v){0.f, 0.f, 0.f, 0.f};

    #pragma unroll
    for (int kk = 0; kk < 8; kk++) {
        half8 b0f[4], b1f[4], a0f[4], a1f[4];
        #pragma unroll
        for (int n = 0; n < 4; n++) {
            int nf = (w << 2) + n;
            size_t off = (size_t)(((kk << 4) + nf) << 6 | l) << 3;
            b0f[n] = *(const half8*)(B0p + off);
            b1f[n] = *(const half8*)(B1p + off);
        }
        #pragma unroll
        for (int m = 0; m < 4; m++) {
            int base = (((kk << 2) + m) << 6 | l) << 3;
            a0f[m] = *(const half8*)&A0[base];
            a1f[m] = *(const half8*)&A1[base];
        }
        #pragma unroll
        for (int m = 0; m < 4; m++)
            #pragma unroll
            for (int n = 0; n < 4; n++) {
                acc[m][n] = __builtin_amdgcn_mfma_f32_16x16x32_f16(a0f[m], b0f[n], acc[m][n], 0, 0, 0);
                acc[m][n] = __builtin_amdgcn_mfma_f32_16x16x32_f16(a0f[m], b1f[n], acc[m][n], 0, 0, 0);
                acc[m][n] = __builtin_amdgcn_mfma_f32_16x16x32_f16(a1f[m], b0f[n], acc[m][n], 0, 0, 0);
            }
    }

    // ---- epilogue: bias + relu, e2 row-dots, emb col partials ----
    // C frag layout: col = w*64 + n*16 + (l&15), row = m*16 + (l>>4)*4 + j
    const int colbase = (w << 6) + frow;
    float w20[4], w21[4], b1v[4];
    #pragma unroll
    for (int n = 0; n < 4; n++) {
        int c = colbase + (n << 4);
        b1v[n] = b1[c];
        w20[n] = W2[2 * c];
        w21[n] = W2[2 * c + 1];
    }
    float ps0[4][4], ps1[4][4], embp[4] = {0.f, 0.f, 0.f, 0.f};
    #pragma unroll
    for (int m = 0; m < 4; m++)
        #pragma unroll
        for (int j = 0; j < 4; j++) { ps0[m][j] = 0.f; ps1[m][j] = 0.f; }

    #pragma unroll
    for (int m = 0; m < 4; m++)
        #pragma unroll
        for (int n = 0; n < 4; n++)
            #pragma unroll
            for (int j = 0; j < 4; j++) {
                float h = fmaxf(acc[m][n][j] + b1v[n], 0.f);
                ps0[m][j] += h * w20[n];
                ps1[m][j] += h * w21[n];
                int row = (m << 4) + (fk << 2) + j;
                if (row < BMV) embp[n] += h;     // exclude pad row 63
            }

    #pragma unroll
    for (int off = 1; off < 16; off <<= 1)
        #pragma unroll
        for (int m = 0; m < 4; m++)
            #pragma unroll
            for (int j = 0; j < 4; j++) {
                ps0[m][j] += __shfl_xor(ps0[m][j], off);
                ps1[m][j] += __shfl_xor(ps1[m][j], off);
            }
    if (frow == 0) {
        #pragma unroll
        for (int m = 0; m < 4; m++)
            #pragma unroll
            for (int j = 0; j < 4; j++) {
                int row = (m << 4) + (fk << 2) + j;
                red0[w][row] = ps0[m][j];
                red1[w][row] = ps1[m][j];
            }
    }

    #pragma unroll
    for (int n = 0; n < 4; n++) {
        embp[n] += __shfl_xor(embp[n], 16);
        embp[n] += __shfl_xor(embp[n], 32);
    }
    if (l < 16) {
        #pragma unroll
        for (int n = 0; n < 4; n++)
            atomicAdd(emb + (size_t)batch * 256 + (w << 6) + (n << 4) + l, embp[n]);
    }

    __syncthreads();
    if (t < 64) {
        float v0 = red0[0][t] + red0[1][t] + red0[2][t] + red0[3][t] + b2[0];
        float v1 = red1[0][t] + red1[1][t] + red1[2][t] + red1[3][t] + b2[1];
        if (t < BMV) {
            Dreg[row0 + t] = v0;   // raw e2 ch0 (symmetrized later)
            Wreg[row0 + t] = v1;
        }
    }
}

// ---------------------------------------------------------------------------
// Kernel 2: in-place symmetrize + softplus. One thread per unordered pair.
// ---------------------------------------------------------------------------
__global__ __launch_bounds__(256) void sym_kernel(float* __restrict__ Dreg,
                                                  float* __restrict__ Wreg)
{
    int t = blockIdx.x * 256 + threadIdx.x;
    const int PAIRS = (NMAX * (NMAX + 1)) / 2;   // 231
    if (t >= B_SZ * PAIRS) return;
    int b = t / PAIRS, p = t % PAIRS;
    int i = 0;
    while (p >= NMAX - i) { p -= NMAX - i; i++; }
    int j = i + p;
    size_t base = (size_t)b * NN;
    float a0 = Dreg[base + i * NMAX + j], a1 = Dreg[base + j * NMAX + i];
    float d  = (i == j) ? 0.f : softplus_f(a0 + a1);
    Dreg[base + i * NMAX + j] = d; Dreg[base + j * NMAX + i] = d;
    float w0 = Wreg[base + i * NMAX + j], w1 = Wreg[base + j * NMAX + i];
    float ws = softplus_f(w0 + w1);
    Wreg[base + i * NMAX + j] = ws; Wreg[base + j * NMAX + i] = ws;
}

// ---------------------------------------------------------------------------
// Kernel 3: per-batch MDS recon, fully in registers + wave shuffles.
// Lane i (i<21) holds D[i][:], W[i][:], A[i][:] rows and X_i in registers.
// D,W are symmetric => m[i][q] == m[q][i] => no transpose needed in grad.
// Zero barriers in the 30 power steps + 100 GD steps.
// ---------------------------------------------------------------------------
__global__ __launch_bounds__(64) void recon_kernel(
    const float* __restrict__ Dm, const float* __restrict__ Wm,
    const float* __restrict__ un, const float* __restrict__ xn,
    float* __restrict__ Xo)
{
    const int b = blockIdx.x, l = threadIdx.x;
    __shared__ float Ds[NN], Ws[NN];

    const float* Db = Dm + (size_t)b * NN;
    const float* Wb = Wm + (size_t)b * NN;
    for (int idx = l; idx < NN; idx += 64) { Ds[idx] = Db[idx]; Ws[idx] = Wb[idx]; }
    __syncthreads();

    const bool act = (l < NMAX);
    const int rbase = (act ? l : 0) * NMAX;
    float Drow[NMAX], Wrow[NMAX], Arow[NMAX];
    float rs = 0.f;
    #pragma unroll
    for (int q = 0; q < NMAX; q++) {
        float dv = Ds[rbase + q], wv = Ws[rbase + q];
        Drow[q] = act ? dv : 0.f;
        Wrow[q] = act ? wv : 0.f;
        rs += Drow[q];
    }
    // total/mean via butterfly (inactive lanes contribute 0)
    float tot = rs;
    #pragma unroll
    for (int m = 1; m < 64; m <<= 1) tot += __shfl_xor(tot, m);
    const float mean = tot * (1.f / (float)NN);
    const float rsn = rs * (1.f / (float)NMAX);
    #pragma unroll
    for (int q = 0; q < NMAX; q++) {
        float rsq = __shfl(rsn, q);
        float v = -0.5f * (Drow[q] - rsn - rsq + mean);
        Arow[q] = act ? v : 0.f;
    }

    // deflated power iteration: k=3 eigvecs, 10 steps each
    float xr[3] = {0.f, 0.f, 0.f};
    #pragma unroll
    for (int e = 0; e < 3; e++) {
        float u = act ? un[(size_t)b * 63 + e * NMAX + l] : 0.f;
        for (int s = 0; s < 10; s++) {
            float n2 = u * u;
            #pragma unroll
            for (int m = 1; m < 64; m <<= 1) n2 += __shfl_xor(n2, m);
            u *= 1.f / fmaxf(sqrtf(n2), 1e-3f);
            float a = 0.f;
            #pragma unroll
            for (int q = 0; q < NMAX; q++) a = fmaf(Arow[q], __shfl(u, q), a);
            u = act ? a : 0.f;
        }
        float e2 = u * u;
        #pragma unroll
        for (int m = 1; m < 64; m <<= 1) e2 += __shfl_xor(e2, m);
        u *= 1.f / sqrtf(sqrtf(e2 + 0.01f));
        xr[e] = u;
        #pragma unroll
        for (int q = 0; q < NMAX; q++) Arow[q] = fmaf(-u, __shfl(u, q), Arow[q]);
    }
    float x = xr[0], y = xr[1], z = xr[2];
    if (act) {
        x += xn[(size_t)b * 63 + l * 3 + 0];
        y += xn[(size_t)b * 63 + l * 3 + 1];
        z += xn[(size_t)b * 63 + l * 3 + 2];
    }

    // 100 clipped gradient-descent steps (no barriers, no LDS)
    for (int tstep = 0; tstep < 100; tstep++) {
        float gx = 0.f, gy = 0.f, gz = 0.f;
        #pragma unroll
        for (int q = 0; q < NMAX; q++) {
            float dx = x - __shfl(x, q);
            float dy = y - __shfl(y, q);
            float dz = z - __shfl(z, q);
            float s = fmaf(dx, dx, fmaf(dy, dy, fmaf(dz, dz, 0.01f)));
            float cm = Wrow[q] * (Drow[q] - s);
            gx = fmaf(cm, dx, gx);
            gy = fmaf(cm, dy, gy);
            gz = fmaf(cm, dz, gz);
        }
        // dX = 0.8 * sum(m_iq * (X_i - X_q))   [0.4 * (m_iq + m_qi), symmetric]
        float d0 = 0.8f * gx, d1 = 0.8f * gy, d2 = 0.8f * gz;
        float speed = sqrtf(fmaf(d0, d0, fmaf(d1, d1, fmaf(d2, d2, 1e-3f))));
        float alpha = 0.1f + 4.9f * (100.f - (float)tstep) * 0.01f;
        float scale = alpha * tanhf(speed / alpha) / speed;
        x = fmaf(d0, scale, x);
        y = fmaf(d1, scale, y);
        z = fmaf(d2, scale, z);
    }
    if (act) {
        Xo[(size_t)b * 63 + l * 3 + 0] = x;
        Xo[(size_t)b * 63 + l * 3 + 1] = y;
        Xo[(size_t)b * 63 + l * 3 + 2] = z;
    }
}

// ---------------------------------------------------------------------------
extern "C" void kernel_launch(void* const* d_in, const int* in_sizes, int n_in,
                              void* d_out, int out_size, void* d_ws, size_t ws_size,
                              hipStream_t stream) {
    const float* gnn = (const float*)d_in[0];
    const float* W1  = (const float*)d_in[1];
    const float* b1  = (const float*)d_in[2];
    const float* W2  = (const float*)d_in[3];
    const float* b2  = (const float*)d_in[4];
    const float* un  = (const float*)d_in[5];
    const float* xn  = (const float*)d_in[6];

    float* out  = (float*)d_out;
    float* Dreg = out;                                  // [1024*441]
    float* Wreg = out + (size_t)TOT_ROWS;               // [1024*441]
    float* emb  = out + (size_t)2 * TOT_ROWS;           // [1024*256]
    float* Xo   = out + (size_t)2 * TOT_ROWS + B_SZ*256;// [1024*63]

    _Float16* B0p = (_Float16*)d_ws;                    // 65536 halves
    _Float16* B1p = B0p + 65536;                        // 65536 halves

    pack_w1<<<dim3(256), dim3(256), 0, stream>>>(W1, B0p, B1p);
    hipMemsetAsync(emb, 0, (size_t)B_SZ * 256 * sizeof(float), stream);

    fused_mlp_mfma<<<dim3(B_SZ * TILES_PER_BATCH), dim3(256), 0, stream>>>(
        gnn, B0p, B1p, b1, W2, b2, Dreg, Wreg, emb);

    const int PAIRS = (NMAX * (NMAX + 1)) / 2;          // 231
    int sym_threads = B_SZ * PAIRS;                     // 236544
    sym_kernel<<<dim3((sym_threads + 255) / 256), dim3(256), 0, stream>>>(Dreg, Wreg);

    recon_kernel<<<dim3(B_SZ), dim3(64), 0, stream>>>(Dreg, Wreg, un, xn, Xo);
}